// Round 7
// baseline (78.435 us; speedup 1.0000x reference)
//
#include <hip/hip_runtime.h>
#include <math.h>

// Problem constants (fixed by setup_inputs): C=64 channels, HW=128*128, bins=256.
#define C_CH 64
#define HW   16384
#define BINS 256

__device__ inline float4 ld4(const float* p) { return *(const float4*)p; }

__device__ inline int lbound(const float* a, float rank) {
    int lo = 0, hi = BINS;
    while (lo < hi) { int mid = (lo + hi) >> 1; if (a[mid] < rank) lo = mid + 1; else hi = mid; }
    return (lo > 255) ? 255 : lo;   // cannot trigger (a[255]=N>=rank); defensive
}

// One fused kernel: 64 blocks (one channel each) x 1024 threads (16 contiguous
// elems/thread). Each block independently computes:
//   A: channel-c histogram of match*mask -> scdf (min/max via wave shuffles,
//      LDS atomics with exact-zero sidecount, wave-0 shuffle scan)
//   B: (c!=0) redundant channel-0 histogram -> cdf0 (ch0 data is L2/L3-hot);
//      (c==0) copy
//   C: channel-0 input*mask min/max (streaming)
//   D: T LUT from cdf0 + ch0 stats
//   E: marching-pointer CDF-inversion loss over its channel
//   F: non-blocking finale: publish packed {flag,sse} u64 via atomicExch; the
//      block that sees all 64 flags set wave-reduces and writes out[0].
//      (Ties write the same deterministic value; poison 0xAA != flag. The
//      last block to publish is guaranteed to see all 64: its exch completes
//      before the barrier drains vmcnt, and atomic-RMW reads return the
//      latest value in each cell's modification order.)
__global__ __launch_bounds__(1024, 4) void fused(const float* __restrict__ input,
                                                 const float* __restrict__ match,
                                                 const float* __restrict__ mask,
                                                 unsigned long long* __restrict__ pub,
                                                 float* __restrict__ out) {
    const int c = blockIdx.x, tid = threadIdx.x;
    const int wave = tid >> 6, lane = tid & 63;

    __shared__ float wa[16], wb[16], wc[16];
    __shared__ int   wzi[16];
    __shared__ int   hist[BINS];
    __shared__ float scdf[BINS], cdf0[BINS], sT[BINS];

    // mask in regs, reused by every phase (element i = 16*tid + j)
    const float* mkp = mask + 16 * tid;
    float kv[16];
    #pragma unroll
    for (int k = 0; k < 4; k++) {
        float4 t = ld4(mkp + 4 * k);
        kv[4 * k] = t.x; kv[4 * k + 1] = t.y; kv[4 * k + 2] = t.z; kv[4 * k + 3] = t.w;
    }
    float msum = 0.0f;
    #pragma unroll
    for (int j = 0; j < 16; j++) msum += kv[j];
    #pragma unroll
    for (int s = 32; s > 0; s >>= 1) msum += __shfl_xor(msum, s, 64);

    // ---------------- phase A: channel-c histogram -> scdf ----------------
    float v[16];
    {
        const float* mp = match + c * HW + 16 * tid;
        float mn = INFINITY, mx = -INFINITY;
        #pragma unroll
        for (int k = 0; k < 4; k++) {
            float4 t = ld4(mp + 4 * k);
            v[4 * k] = t.x * kv[4 * k];       v[4 * k + 1] = t.y * kv[4 * k + 1];
            v[4 * k + 2] = t.z * kv[4 * k + 2]; v[4 * k + 3] = t.w * kv[4 * k + 3];
        }
        #pragma unroll
        for (int j = 0; j < 16; j++) { mn = fminf(mn, v[j]); mx = fmaxf(mx, v[j]); }
        #pragma unroll
        for (int s = 32; s > 0; s >>= 1) {
            mn = fminf(mn, __shfl_xor(mn, s, 64));
            mx = fmaxf(mx, __shfl_xor(mx, s, 64));
        }
        if (lane == 0) { wa[wave] = mn; wb[wave] = mx; wc[wave] = msum; }
        if (tid < BINS) hist[tid] = 0;
        __syncthreads();                                   // B1
        mn = wa[0]; mx = wb[0];
        msum = wc[0];
        #pragma unroll
        for (int j = 1; j < 16; j++) {
            mn = fminf(mn, wa[j]);
            mx = fmaxf(mx, wb[j]);
            msum += wc[j];                                 // FIX (R6 bug): fold ALL waves
        }

        // torch.histc: w=(mx-mn)/bins; safe_w = w>0 ? w : 1  (/256 exact)
        float w = (mx - mn) * (1.0f / 256.0f);
        float sw = (w > 0.0f) ? w : 1.0f;

        int zc = 0;
        #pragma unroll
        for (int j = 0; j < 16; j++) {
            if (v[j] == 0.0f) { zc++; }                    // ~30% masked zeros: no atomic
            else {
                float bb = floorf((v[j] - mn) / sw);
                bb = fminf(fmaxf(bb, 0.0f), 255.0f);       // clip in float like the ref
                atomicAdd(&hist[(int)bb], 1);
            }
        }
        #pragma unroll
        for (int s = 32; s > 0; s >>= 1) zc += __shfl_xor(zc, s, 64);
        if (lane == 0) wzi[wave] = zc;
        __syncthreads();                                   // B2
        if (tid == 0) {
            int z = 0;
            #pragma unroll
            for (int j = 0; j < 16; j++) z += wzi[j];
            float bb = floorf((0.0f - mn) / sw);           // bin of v==0 (same calc)
            bb = fminf(fmaxf(bb, 0.0f), 255.0f);
            hist[(int)bb] += z;
        }
        __syncthreads();                                   // B3
        if (wave == 0) {                                   // shuffle scan, 4 bins/lane
            int h0 = hist[4 * lane], h1 = hist[4 * lane + 1];
            int h2 = hist[4 * lane + 2], h3 = hist[4 * lane + 3];
            int p1 = h0 + h1, p2 = p1 + h2, s4 = p2 + h3;
            int sc = s4;
            #pragma unroll
            for (int off = 1; off < 64; off <<= 1) {
                int t = __shfl_up(sc, off, 64);
                if (lane >= off) sc += t;
            }
            int e = sc - s4;
            scdf[4 * lane] = (float)(e + h0);  scdf[4 * lane + 1] = (float)(e + p1);
            scdf[4 * lane + 2] = (float)(e + p2); scdf[4 * lane + 3] = (float)(e + s4);
        }
        __syncthreads();                                   // B4
    }

    // ------------- phase B: channel-0 histogram -> cdf0 (redundant) -------------
    if (c != 0) {
        const float* mp = match + 16 * tid;                // channel 0, L2/L3-hot
        float mn = INFINITY, mx = -INFINITY;
        #pragma unroll
        for (int k = 0; k < 4; k++) {
            float4 t = ld4(mp + 4 * k);
            v[4 * k] = t.x * kv[4 * k];       v[4 * k + 1] = t.y * kv[4 * k + 1];
            v[4 * k + 2] = t.z * kv[4 * k + 2]; v[4 * k + 3] = t.w * kv[4 * k + 3];
        }
        #pragma unroll
        for (int j = 0; j < 16; j++) { mn = fminf(mn, v[j]); mx = fmaxf(mx, v[j]); }
        #pragma unroll
        for (int s = 32; s > 0; s >>= 1) {
            mn = fminf(mn, __shfl_xor(mn, s, 64));
            mx = fmaxf(mx, __shfl_xor(mx, s, 64));
        }
        if (lane == 0) { wa[wave] = mn; wb[wave] = mx; }
        if (tid < BINS) hist[tid] = 0;
        __syncthreads();                                   // B5
        mn = wa[0]; mx = wb[0];
        #pragma unroll
        for (int j = 1; j < 16; j++) { mn = fminf(mn, wa[j]); mx = fmaxf(mx, wb[j]); }
        float w = (mx - mn) * (1.0f / 256.0f);
        float sw = (w > 0.0f) ? w : 1.0f;
        int zc = 0;
        #pragma unroll
        for (int j = 0; j < 16; j++) {
            if (v[j] == 0.0f) { zc++; }
            else {
                float bb = floorf((v[j] - mn) / sw);
                bb = fminf(fmaxf(bb, 0.0f), 255.0f);
                atomicAdd(&hist[(int)bb], 1);
            }
        }
        #pragma unroll
        for (int s = 32; s > 0; s >>= 1) zc += __shfl_xor(zc, s, 64);
        if (lane == 0) wzi[wave] = zc;
        __syncthreads();                                   // B6
        if (tid == 0) {
            int z = 0;
            #pragma unroll
            for (int j = 0; j < 16; j++) z += wzi[j];
            float bb = floorf((0.0f - mn) / sw);
            bb = fminf(fmaxf(bb, 0.0f), 255.0f);
            hist[(int)bb] += z;
        }
        __syncthreads();                                   // B7
        if (wave == 0) {
            int h0 = hist[4 * lane], h1 = hist[4 * lane + 1];
            int h2 = hist[4 * lane + 2], h3 = hist[4 * lane + 3];
            int p1 = h0 + h1, p2 = p1 + h2, s4 = p2 + h3;
            int sc = s4;
            #pragma unroll
            for (int off = 1; off < 64; off <<= 1) {
                int t = __shfl_up(sc, off, 64);
                if (lane >= off) sc += t;
            }
            int e = sc - s4;
            cdf0[4 * lane] = (float)(e + h0);  cdf0[4 * lane + 1] = (float)(e + p1);
            cdf0[4 * lane + 2] = (float)(e + p2); cdf0[4 * lane + 3] = (float)(e + s4);
        }
        __syncthreads();                                   // B8
    } else {
        if (tid < BINS) cdf0[tid] = scdf[tid];
        __syncthreads();
    }

    // ------------- phase C: channel-0 input*mask min/max (streaming) -------------
    float xmn = INFINITY, xmx = -INFINITY;
    {
        const float* ip = input + 16 * tid;                // channel 0, hot
        #pragma unroll
        for (int k = 0; k < 4; k++) {
            float4 t = ld4(ip + 4 * k);
            float a = t.x * kv[4 * k],     b2 = t.y * kv[4 * k + 1];
            float d = t.z * kv[4 * k + 2], e = t.w * kv[4 * k + 3];
            xmn = fminf(xmn, fminf(fminf(a, b2), fminf(d, e)));
            xmx = fmaxf(xmx, fmaxf(fmaxf(a, b2), fmaxf(d, e)));
        }
        #pragma unroll
        for (int s = 32; s > 0; s >>= 1) {
            xmn = fminf(xmn, __shfl_xor(xmn, s, 64));
            xmx = fmaxf(xmx, __shfl_xor(xmx, s, 64));
        }
        if (lane == 0) { wa[wave] = xmn; wb[wave] = xmx; }
        __syncthreads();                                   // B9
        xmn = wa[0]; xmx = wb[0];
        #pragma unroll
        for (int j = 1; j < 16; j++) { xmn = fminf(xmn, wa[j]); xmx = fmaxf(xmx, wb[j]); }
    }

    // ------------- phase D: T LUT -------------
    if (tid < BINS) {
        float step = (xmx - xmn) * (1.0f / 256.0f);
        float rank = (float)(tid + 1);
        int idx = lbound(cdf0, rank);
        float cp = (idx > 0) ? cdf0[idx - 1] : 0.0f;
        float cc = cdf0[idx];
        float ratio = fminf(fmaxf((rank - cp) / (1e-8f + cc), 0.0f), 1.0f);
        sT[tid] = xmn + (ratio + (float)idx) * step;
    }
    __syncthreads();                                       // B10

    // ------------- phase E: loss over channel c -------------
    float acc = 0.0f;
    {
        const float* xp = input + c * HW + 16 * tid;
        int lo = lbound(scdf, (float)(16 * tid + 1));      // one search, then march
        #pragma unroll
        for (int k = 0; k < 4; k++) {
            float4 t = ld4(xp + 4 * k);
            float vv[4] = { t.x * kv[4 * k], t.y * kv[4 * k + 1],
                            t.z * kv[4 * k + 2], t.w * kv[4 * k + 3] };
            float r0 = (float)(16 * tid + 4 * k + 1);
            #pragma unroll
            for (int j = 0; j < 4; j++) {
                float rnk = r0 + (float)j;
                while (scdf[lo] < rnk) lo++;               // scdf[255]=N bounds it
                float d = sT[lo] - vv[j];
                acc += d * d;
            }
        }
        #pragma unroll
        for (int s = 32; s > 0; s >>= 1) acc += __shfl_xor(acc, s, 64);
        if (lane == 0) wa[wave] = acc;
        __syncthreads();                                   // B11
    }

    // ------------- phase F: non-blocking finale -------------
    if (tid == 0) {
        float tot = 0.0f;
        #pragma unroll
        for (int j = 0; j < 16; j++) tot += wa[j];
        unsigned long long pk = (1ULL << 32) | (unsigned long long)__float_as_uint(tot);
        atomicExch(&pub[c], pk);
    }
    __syncthreads();                                       // B12: own publish first
    if (wave == 0) {
        unsigned long long vv = atomicAdd(&pub[lane], 0ULL);   // lane <-> block
        bool got = ((vv >> 32) == 1ULL);
        unsigned long long bal = __ballot(got);
        float p = got ? __uint_as_float((unsigned int)vv) : 0.0f;
        #pragma unroll
        for (int s = 32; s > 0; s >>= 1) p += __shfl_xor(p, s, 64);
        if (lane == 0 && bal == ~0ULL) {                   // saw all 64: finalize
            double loss = (double)p * (double)msum /
                          ((double)C_CH * (double)HW * (double)HW);
            out[0] = (float)loss;
        }
    }
}

extern "C" void kernel_launch(void* const* d_in, const int* in_sizes, int n_in,
                              void* d_out, int out_size, void* d_ws, size_t ws_size,
                              hipStream_t stream) {
    const float* input = (const float*)d_in[0];
    const float* match = (const float*)d_in[1];
    const float* mask  = (const float*)d_in[2];
    unsigned long long* pub = (unsigned long long*)d_ws;   // 64 cells
    float* out = (float*)d_out;

    fused<<<C_CH, 1024, 0, stream>>>(input, match, mask, pub, out);
}